// Round 1
// baseline (151.808 us; speedup 1.0000x reference)
//
#include <hip/hip_runtime.h>
#include <stdint.h>

#define B_ROWS 4096
#define C_OUT  2048
#define C_IN   2048
#define EPS    1e-5f

typedef __attribute__((ext_vector_type(8))) short bf16x8;  // 8 bf16 = 4 VGPRs
typedef __attribute__((ext_vector_type(4))) float f32x4;

// RNE f32 -> bf16
__device__ __forceinline__ unsigned short f2bf(float f) {
    uint32_t u = __float_as_uint(f);
    uint32_t r = (u + 0x7fffu + ((u >> 16) & 1u)) >> 16;
    return (unsigned short)r;
}

__global__ void cvt_f32_bf16_kernel(const float* __restrict__ in,
                                    unsigned short* __restrict__ out, int n4) {
    int i = blockIdx.x * blockDim.x + threadIdx.x;
    if (i < n4) {
        float4 v = ((const float4*)in)[i];
        ushort4 o;
        o.x = f2bf(v.x); o.y = f2bf(v.y); o.z = f2bf(v.z); o.w = f2bf(v.w);
        ((ushort4*)out)[i] = o;
    }
}

// Fused bf16 GEMM (C = A @ W^T + bias) + GroupNorm(32 groups of 64) + hardtanh.
// Tile 128x128, BK=32, 4 waves (2x2 of 64x64). Each wave's 64 cols == one GN group.
__global__ void gemm_gn_kernel(const unsigned short* __restrict__ A,  // [4096][2048] bf16
                               const unsigned short* __restrict__ W,  // [2048][2048] bf16
                               const float* __restrict__ bias,
                               const float* __restrict__ gnw,
                               const float* __restrict__ gnb,
                               float* __restrict__ out) {
    // No padding: global_load_lds dest is wave-uniform base + lane*16 (m104/m108)
    __shared__ unsigned short sA[128 * 32];
    __shared__ unsigned short sB[128 * 32];

    const int bc   = blockIdx.x;      // 0..15 col block
    const int br   = blockIdx.y;      // 0..31 row block
    const int t    = threadIdx.x;     // 0..255
    const int lane = t & 63;
    const int wave = t >> 6;
    const int wr   = wave >> 1;       // wave row half
    const int wc   = wave & 1;        // wave col half
    const int c16  = lane & 15;
    const int quad = lane >> 4;

    f32x4 acc[4][4];
#pragma unroll
    for (int i = 0; i < 4; i++)
#pragma unroll
        for (int j = 0; j < 4; j++) acc[i][j] = (f32x4){0.f, 0.f, 0.f, 0.f};

    // staging: issue j covers rows [64j, 64j+64); thread t -> flat elem j*2048 + t*8
    const int fl0 = t * 8;            // element offset in tile (row = fl0/32, k = fl0%32)
    const int r0  = fl0 >> 5;
    const int kk0 = fl0 & 31;
    const unsigned short* gA = A + (size_t)(br * 128 + r0) * C_IN + kk0;
    const unsigned short* gB = W + (size_t)(bc * 128 + r0) * C_IN + kk0;

    for (int k0 = 0; k0 < C_IN; k0 += 32) {
        __builtin_amdgcn_global_load_lds(
            (const __attribute__((address_space(1))) void*)(gA + k0),
            (__attribute__((address_space(3))) void*)(sA + fl0), 16, 0, 0);
        __builtin_amdgcn_global_load_lds(
            (const __attribute__((address_space(1))) void*)(gA + (size_t)64 * C_IN + k0),
            (__attribute__((address_space(3))) void*)(sA + 2048 + fl0), 16, 0, 0);
        __builtin_amdgcn_global_load_lds(
            (const __attribute__((address_space(1))) void*)(gB + k0),
            (__attribute__((address_space(3))) void*)(sB + fl0), 16, 0, 0);
        __builtin_amdgcn_global_load_lds(
            (const __attribute__((address_space(1))) void*)(gB + (size_t)64 * C_IN + k0),
            (__attribute__((address_space(3))) void*)(sB + 2048 + fl0), 16, 0, 0);
        __syncthreads();   // drains vmcnt before barrier -> staging complete

        bf16x8 a[4], b[4];
#pragma unroll
        for (int i = 0; i < 4; i++) {
            // A-frag: m = lane&15, k = quad*8 + j (m89-verified operand layout)
            a[i] = *(const bf16x8*)(sA + (wr * 64 + i * 16 + c16) * 32 + quad * 8);
            b[i] = *(const bf16x8*)(sB + (wc * 64 + i * 16 + c16) * 32 + quad * 8);
        }
#pragma unroll
        for (int i = 0; i < 4; i++)
#pragma unroll
            for (int j = 0; j < 4; j++)
                acc[i][j] = __builtin_amdgcn_mfma_f32_16x16x32_bf16(a[i], b[j], acc[i][j], 0, 0, 0);
        __syncthreads();   // before next staging overwrite
    }

    // ---- epilogue: bias + GroupNorm + hardtanh ----
    // acc[i][j][r] is C[row][col], row = br*128 + wr*64 + i*16 + quad*4 + r,
    //                              col = bc*128 + wc*64 + j*16 + c16.
    // Wave's 64 cols == one group: reduce over j (4 tiles) and 16 lanes of same quad.
    const int colbase = bc * 128 + wc * 64;
    const int rowbase = br * 128 + wr * 64;
    float bv[4], gw[4], gb[4];
#pragma unroll
    for (int j = 0; j < 4; j++) {
        int col = colbase + j * 16 + c16;
        bv[j] = bias[col];
        gw[j] = gnw[col];
        gb[j] = gnb[col];
    }
#pragma unroll
    for (int i = 0; i < 4; i++) {
#pragma unroll
        for (int r = 0; r < 4; r++) {
            float s = 0.f, ss = 0.f;
#pragma unroll
            for (int j = 0; j < 4; j++) {
                float v = acc[i][j][r] + bv[j];
                acc[i][j][r] = v;
                s += v;
                ss += v * v;
            }
            // reduce across the 16 lanes sharing this row (xor within quad group)
#pragma unroll
            for (int m = 1; m < 16; m <<= 1) {
                s  += __shfl_xor(s, m, 64);
                ss += __shfl_xor(ss, m, 64);
            }
            float mean = s * (1.f / 64.f);
            float var  = ss * (1.f / 64.f) - mean * mean;
            float rstd = rsqrtf(var + EPS);
            int row = rowbase + i * 16 + quad * 4 + r;
            float* orow = out + (size_t)row * C_OUT;
#pragma unroll
            for (int j = 0; j < 4; j++) {
                float v = (acc[i][j][r] - mean) * rstd * gw[j] + gb[j];
                v = fminf(1.f, fmaxf(-1.f, v));
                orow[colbase + j * 16 + c16] = v;
            }
        }
    }
}

extern "C" void kernel_launch(void* const* d_in, const int* in_sizes, int n_in,
                              void* d_out, int out_size, void* d_ws, size_t ws_size,
                              hipStream_t stream) {
    const float* x    = (const float*)d_in[0];   // [4096, 2048]
    const float* w    = (const float*)d_in[1];   // [2048, 2048]
    const float* bias = (const float*)d_in[2];   // [2048]
    const float* gnw  = (const float*)d_in[3];   // [2048]
    const float* gnb  = (const float*)d_in[4];   // [2048]
    float* out = (float*)d_out;

    unsigned short* xb = (unsigned short*)d_ws;                        // 16 MB
    unsigned short* wb = xb + (size_t)B_ROWS * C_IN;                   //  8 MB

    const int nx = B_ROWS * C_IN;   // 8388608
    const int nw = C_OUT * C_IN;    // 4194304
    cvt_f32_bf16_kernel<<<(nx / 4 + 255) / 256, 256, 0, stream>>>(x, xb, nx / 4);
    cvt_f32_bf16_kernel<<<(nw / 4 + 255) / 256, 256, 0, stream>>>(w, wb, nw / 4);

    dim3 grid(C_OUT / 128, B_ROWS / 128);  // (16, 32)
    gemm_gn_kernel<<<grid, 256, 0, stream>>>(xb, wb, bias, gnw, gnb, out);
}